// Round 5
// baseline (95.531 us; speedup 1.0000x reference)
//
#include <hip/hip_runtime.h>

// N-body all-pairs gravitational force, N=8192, fp32.
//
// Round-5: IBLK=4 (quarters LDS-pipe pressure + loop overhead per pair,
// 4 independent rsq/FMA chains), 2 launches total:
//  - pack_zero: d_ws <- float4{x,y,z,m}; d_out <- 0
//  - nbody:     grid (8,128) = 1024 blocks = 4 waves/SIMD; one 1 KB LDS
//               tile, ONE barrier; atomicAdd epilogue (no reduce pass).
// Issue-bound floor: 67.1M pairs -> 13 insts/pair -> ~13.7 us.

constexpr int   NBODY   = 8192;
constexpr int   BLOCK   = 256;
constexpr int   IBLK    = 4;
constexpr int   IBODIES = BLOCK * IBLK;        // 1024 i's per block
constexpr int   JSPLIT  = 128;
constexpr int   JPER    = NBODY / JSPLIT;      // 64 j's per block
constexpr float SOFT2   = 0.01f * 0.01f;

__global__ __launch_bounds__(256) void pack_zero_kernel(
    const float* __restrict__ pos, const float* __restrict__ mass,
    float4* __restrict__ packed, float* __restrict__ out)
{
    const int j = blockIdx.x * blockDim.x + threadIdx.x;   // 0..8191
    packed[j] = make_float4(pos[3 * j + 0], pos[3 * j + 1], pos[3 * j + 2], mass[j]);
    out[3 * j + 0] = 0.f;
    out[3 * j + 1] = 0.f;
    out[3 * j + 2] = 0.f;
}

__global__ __launch_bounds__(BLOCK, 4) void nbody_forces(
    const float4* __restrict__ packed,   // [N] {x,y,z,m}
    float*        __restrict__ out)      // [N*3], pre-zeroed
{
    const int tid   = threadIdx.x;
    const int iBase = blockIdx.x * IBODIES + tid;
    const int j0    = blockIdx.y * JPER;

    __shared__ float4 sh[JPER];
    if (tid < JPER) sh[tid] = packed[j0 + tid];

    float px[IBLK], py[IBLK], pz[IBLK];
    #pragma unroll
    for (int b = 0; b < IBLK; ++b) {
        const float4 p = packed[iBase + b * BLOCK];
        px[b] = p.x; py[b] = p.y; pz[b] = p.z;
    }
    __syncthreads();

    float fx[IBLK], fy[IBLK], fz[IBLK];
    #pragma unroll
    for (int b = 0; b < IBLK; ++b) { fx[b] = 0.f; fy[b] = 0.f; fz[b] = 0.f; }

    #pragma unroll 4
    for (int k = 0; k < JPER; ++k) {
        const float4 p = sh[k];            // uniform addr -> HW broadcast
        #pragma unroll
        for (int b = 0; b < IBLK; ++b) {   // 4 independent chains
            const float dx = p.x - px[b];
            const float dy = p.y - py[b];
            const float dz = p.z - pz[b];
            const float d2 = fmaf(dx, dx, fmaf(dy, dy, fmaf(dz, dz, SOFT2)));
            const float inv = __builtin_amdgcn_rsqf(d2);    // v_rsq_f32
            const float s   = p.w * inv * inv * inv;        // G = 1
            fx[b] = fmaf(s, dx, fx[b]);
            fy[b] = fmaf(s, dy, fy[b]);
            fz[b] = fmaf(s, dz, fz[b]);
            // j == i: diff = 0 -> contribution 0, matches reference.
        }
    }

    #pragma unroll
    for (int b = 0; b < IBLK; ++b) {
        const int i = iBase + b * BLOCK;
        atomicAdd(&out[3 * i + 0], fx[b]);
        atomicAdd(&out[3 * i + 1], fy[b]);
        atomicAdd(&out[3 * i + 2], fz[b]);
    }
}

extern "C" void kernel_launch(void* const* d_in, const int* in_sizes, int n_in,
                              void* d_out, int out_size, void* d_ws, size_t ws_size,
                              hipStream_t stream) {
    const float* pos  = (const float*)d_in[0];
    const float* mass = (const float*)d_in[1];
    float* out = (float*)d_out;

    float4* packed = (float4*)d_ws;

    pack_zero_kernel<<<NBODY / 256, 256, 0, stream>>>(pos, mass, packed, out);

    dim3 grid(NBODY / IBODIES, JSPLIT);   // (8, 128) = 1024 blocks
    nbody_forces<<<grid, BLOCK, 0, stream>>>(packed, out);
}

// Round 6
// 86.755 us; speedup vs baseline: 1.1012x; 1.1012x over previous
//
#include <hip/hip_runtime.h>

// N-body all-pairs gravitational force, N=8192, fp32.
//
// Round-6: round-5 compute (IBLK=4, 4 indep rsq/FMA chains, 1024 blocks =
// 4 waves/SIMD) + round-4 epilogue (plain partial stores + reduce pass).
// Round-5's atomicAdd epilogue thrashed: 3.1M device-scope atomics,
// 128 blocks per output line across 8 XCDs -> WRITE_SIZE 36MB, 43us.
// Deterministic stores stream 12.6MB instead (~2us at HBM BW).

constexpr int   NBODY   = 8192;
constexpr int   BLOCK   = 256;
constexpr int   IBLK    = 4;
constexpr int   IBODIES = BLOCK * IBLK;        // 1024 i's per block
constexpr int   JSPLIT  = 128;
constexpr int   JPER    = NBODY / JSPLIT;      // 64 j's per block
constexpr float SOFT2   = 0.01f * 0.01f;
constexpr int   OUTE    = NBODY * 3;           // 24576

__global__ __launch_bounds__(256) void pack_kernel(
    const float* __restrict__ pos, const float* __restrict__ mass,
    float4* __restrict__ packed)
{
    const int j = blockIdx.x * blockDim.x + threadIdx.x;   // 0..8191
    packed[j] = make_float4(pos[3 * j + 0], pos[3 * j + 1], pos[3 * j + 2], mass[j]);
}

__global__ __launch_bounds__(BLOCK, 4) void nbody_forces(
    const float4* __restrict__ packed,   // [N] {x,y,z,m}
    float*        __restrict__ part)     // [JSPLIT][N*3] partials
{
    const int tid   = threadIdx.x;
    const int iBase = blockIdx.x * IBODIES + tid;
    const int j0    = blockIdx.y * JPER;

    __shared__ float4 sh[JPER];
    if (tid < JPER) sh[tid] = packed[j0 + tid];

    float px[IBLK], py[IBLK], pz[IBLK];
    #pragma unroll
    for (int b = 0; b < IBLK; ++b) {
        const float4 p = packed[iBase + b * BLOCK];
        px[b] = p.x; py[b] = p.y; pz[b] = p.z;
    }
    __syncthreads();

    float fx[IBLK], fy[IBLK], fz[IBLK];
    #pragma unroll
    for (int b = 0; b < IBLK; ++b) { fx[b] = 0.f; fy[b] = 0.f; fz[b] = 0.f; }

    #pragma unroll 4
    for (int k = 0; k < JPER; ++k) {
        const float4 p = sh[k];            // uniform addr -> HW broadcast
        #pragma unroll
        for (int b = 0; b < IBLK; ++b) {   // 4 independent chains
            const float dx = p.x - px[b];
            const float dy = p.y - py[b];
            const float dz = p.z - pz[b];
            const float d2 = fmaf(dx, dx, fmaf(dy, dy, fmaf(dz, dz, SOFT2)));
            const float inv = __builtin_amdgcn_rsqf(d2);    // v_rsq_f32
            const float s   = p.w * inv * inv * inv;        // G = 1
            fx[b] = fmaf(s, dx, fx[b]);
            fy[b] = fmaf(s, dy, fy[b]);
            fz[b] = fmaf(s, dz, fz[b]);
            // j == i: diff = 0 -> contribution 0, matches reference.
        }
    }

    float* dst = part + (size_t)blockIdx.y * OUTE;
    #pragma unroll
    for (int b = 0; b < IBLK; ++b) {
        const int i = iBase + b * BLOCK;
        dst[3 * i + 0] = fx[b];
        dst[3 * i + 1] = fy[b];
        dst[3 * i + 2] = fz[b];
    }
}

__global__ __launch_bounds__(256) void reduce_kernel(
    const float* __restrict__ part,      // [JSPLIT][OUTE]
    float*       __restrict__ out)       // [OUTE]
{
    const int e = blockIdx.x * blockDim.x + threadIdx.x;   // 0..OUTE-1
    float s = 0.f;
    #pragma unroll 8
    for (int k = 0; k < JSPLIT; ++k)
        s += part[(size_t)k * OUTE + e];
    out[e] = s;
}

extern "C" void kernel_launch(void* const* d_in, const int* in_sizes, int n_in,
                              void* d_out, int out_size, void* d_ws, size_t ws_size,
                              hipStream_t stream) {
    const float* pos  = (const float*)d_in[0];
    const float* mass = (const float*)d_in[1];
    float* out = (float*)d_out;

    float4* packed = (float4*)d_ws;
    float*  part   = (float*)((char*)d_ws + (size_t)NBODY * sizeof(float4));

    pack_kernel<<<NBODY / 256, 256, 0, stream>>>(pos, mass, packed);

    dim3 grid(NBODY / IBODIES, JSPLIT);   // (8, 128) = 1024 blocks
    nbody_forces<<<grid, BLOCK, 0, stream>>>(packed, part);

    reduce_kernel<<<OUTE / 256, 256, 0, stream>>>(part, out);
}

// Round 7
// 80.762 us; speedup vs baseline: 1.1829x; 1.0742x over previous
//
#include <hip/hip_runtime.h>

// N-body all-pairs gravitational force, N=8192, fp32.
//
// Round-7: first config with ALL of: 4 waves/SIMD (TLP), IBLK=4 (ILP),
// JSPLIT=64 (minimal partial traffic), fused staging (no pack kernel).
//  - BLOCK=128, IBLK=4 -> 512 i's/block, 16 i-tiles
//  - JSPLIT=64 -> JPER=128 j's/block, 2KB LDS tile, ONE barrier
//  - grid 16x64 = 1024 blocks x 2 waves = 4 waves/SIMD
//  - epilogue: plain partial stores [64][N*3] + reduce pass (r5 showed
//    atomics at high split thrash cross-XCD; stores stream 6.3MB ~1us)
// Floor: 262144 wave-k-iters x ~112cyc / 1024 SIMDs ~= 12us.

constexpr int   NBODY   = 8192;
constexpr int   BLOCK   = 128;
constexpr int   IBLK    = 4;
constexpr int   IBODIES = BLOCK * IBLK;        // 512 i's per block
constexpr int   JSPLIT  = 64;
constexpr int   JPER    = NBODY / JSPLIT;      // 128 j's per block
constexpr float SOFT2   = 0.01f * 0.01f;
constexpr int   OUTE    = NBODY * 3;           // 24576

__global__ __launch_bounds__(BLOCK, 8) void nbody_forces(
    const float* __restrict__ pos,       // [N,3]
    const float* __restrict__ mass,      // [N]
    float*       __restrict__ part)      // [JSPLIT][N*3] partials
{
    const int tid   = threadIdx.x;
    const int iBase = blockIdx.x * IBODIES + tid;
    const int j0    = blockIdx.y * JPER;

    __shared__ float4 sh[JPER];          // JPER == BLOCK: every thread stages one j
    {
        const int j = j0 + tid;
        sh[tid] = make_float4(pos[3 * j + 0], pos[3 * j + 1], pos[3 * j + 2], mass[j]);
    }

    float px[IBLK], py[IBLK], pz[IBLK];
    #pragma unroll
    for (int b = 0; b < IBLK; ++b) {
        const int i = iBase + b * BLOCK;
        px[b] = pos[3 * i + 0];
        py[b] = pos[3 * i + 1];
        pz[b] = pos[3 * i + 2];
    }
    __syncthreads();

    float fx[IBLK], fy[IBLK], fz[IBLK];
    #pragma unroll
    for (int b = 0; b < IBLK; ++b) { fx[b] = 0.f; fy[b] = 0.f; fz[b] = 0.f; }

    #pragma unroll 4
    for (int k = 0; k < JPER; ++k) {
        const float4 p = sh[k];            // uniform addr -> HW broadcast
        #pragma unroll
        for (int b = 0; b < IBLK; ++b) {   // 4 independent chains
            const float dx = p.x - px[b];
            const float dy = p.y - py[b];
            const float dz = p.z - pz[b];
            const float d2 = fmaf(dx, dx, fmaf(dy, dy, fmaf(dz, dz, SOFT2)));
            const float inv = __builtin_amdgcn_rsqf(d2);    // v_rsq_f32
            const float s   = p.w * inv * inv * inv;        // G = 1
            fx[b] = fmaf(s, dx, fx[b]);
            fy[b] = fmaf(s, dy, fy[b]);
            fz[b] = fmaf(s, dz, fz[b]);
            // j == i: diff = 0 -> contribution 0, matches reference.
        }
    }

    float* dst = part + (size_t)blockIdx.y * OUTE;
    #pragma unroll
    for (int b = 0; b < IBLK; ++b) {
        const int i = iBase + b * BLOCK;
        dst[3 * i + 0] = fx[b];
        dst[3 * i + 1] = fy[b];
        dst[3 * i + 2] = fz[b];
    }
}

__global__ __launch_bounds__(256) void reduce_kernel(
    const float* __restrict__ part,      // [JSPLIT][OUTE]
    float*       __restrict__ out)       // [OUTE]
{
    const int e = blockIdx.x * blockDim.x + threadIdx.x;   // 0..OUTE-1
    float s = 0.f;
    #pragma unroll 8
    for (int k = 0; k < JSPLIT; ++k)
        s += part[(size_t)k * OUTE + e];
    out[e] = s;
}

extern "C" void kernel_launch(void* const* d_in, const int* in_sizes, int n_in,
                              void* d_out, int out_size, void* d_ws, size_t ws_size,
                              hipStream_t stream) {
    const float* pos  = (const float*)d_in[0];
    const float* mass = (const float*)d_in[1];
    float* out = (float*)d_out;

    float* part = (float*)d_ws;          // [JSPLIT][OUTE] = 6.3 MB

    dim3 grid(NBODY / IBODIES, JSPLIT);  // (16, 64) = 1024 blocks
    nbody_forces<<<grid, BLOCK, 0, stream>>>(pos, mass, part);

    reduce_kernel<<<OUTE / 256, 256, 0, stream>>>(part, out);
}